// Round 12
// baseline (153.984 us; speedup 1.0000x reference)
//
#include <hip/hip_runtime.h>
#include <math.h>

#define NEGV (-1e9f)
#define LOG2E 1.4426950408889634f

typedef _Float16 f16;
typedef __attribute__((ext_vector_type(2))) __fp16 hf2;
typedef __attribute__((ext_vector_type(4))) _Float16 f16x4;
typedef __attribute__((ext_vector_type(4))) float f32x4;

// ---------------------------------------------------------------------------
// prepw: fold consecutive affine layers (computed once, tiny):
//   Wf1[m](48x16) = d1_wo @ d2_wqkv[m];  bf1[m] = d1_bo@d2_wqkv[m] + d2_bqkv[m]
//   Wfp[m](16x16) = d2_wo @ pol_wqkv[m]; bfp[m] = d2_bo@pol_wqkv[m] + pol_bqkv[m]
//   Wfv[m](16x16) = d2_wo @ val_wqkv[m]; bfv[m] = d2_bo@val_wqkv[m] + val_bqkv[m]
// ---------------------------------------------------------------------------
__global__ void prepw_kernel(const float* __restrict__ d1_wo, const float* __restrict__ d1_bo,
                             const float* __restrict__ d2_wqkv, const float* __restrict__ d2_bqkv,
                             const float* __restrict__ d2_wo, const float* __restrict__ d2_bo,
                             const float* __restrict__ pol_wqkv, const float* __restrict__ pol_bqkv,
                             const float* __restrict__ val_wqkv, const float* __restrict__ val_bqkv,
                             float* __restrict__ Wf1, float* __restrict__ bf1,
                             float* __restrict__ Wfp, float* __restrict__ bfp,
                             float* __restrict__ Wfv, float* __restrict__ bfv) {
    int t = blockIdx.x * blockDim.x + threadIdx.x;
    if (t < 2304) {                     // Wf1: mat, r(48), c(16)
        int mat = t / 768, r = (t % 768) / 16, c = t % 16;
        float s = 0.f;
#pragma unroll
        for (int k = 0; k < 16; ++k)
            s = fmaf(d1_wo[r * 16 + k], d2_wqkv[mat * 256 + k * 16 + c], s);
        Wf1[t] = s;
        return;
    }
    int u = t - 2304;
    if (u < 48) {                       // bf1
        int mat = u / 16, c = u % 16;
        float s = d2_bqkv[mat * 16 + c];
#pragma unroll
        for (int k = 0; k < 16; ++k)
            s = fmaf(d1_bo[k], d2_wqkv[mat * 256 + k * 16 + c], s);
        bf1[u] = s;
        return;
    }
    u -= 48;
    if (u < 768) {                      // Wfp
        int mat = u / 256, r = (u % 256) / 16, c = u % 16;
        float s = 0.f;
#pragma unroll
        for (int k = 0; k < 16; ++k)
            s = fmaf(d2_wo[r * 16 + k], pol_wqkv[mat * 256 + k * 16 + c], s);
        Wfp[u] = s;
        return;
    }
    u -= 768;
    if (u < 48) {                       // bfp
        int mat = u / 16, c = u % 16;
        float s = pol_bqkv[mat * 16 + c];
#pragma unroll
        for (int k = 0; k < 16; ++k)
            s = fmaf(d2_bo[k], pol_wqkv[mat * 256 + k * 16 + c], s);
        bfp[u] = s;
        return;
    }
    u -= 48;
    if (u < 768) {                      // Wfv
        int mat = u / 256, r = (u % 256) / 16, c = u % 16;
        float s = 0.f;
#pragma unroll
        for (int k = 0; k < 16; ++k)
            s = fmaf(d2_wo[r * 16 + k], val_wqkv[mat * 256 + k * 16 + c], s);
        Wfv[u] = s;
        return;
    }
    u -= 768;
    if (u < 48) {                       // bfv
        int mat = u / 16, c = u % 16;
        float s = val_bqkv[mat * 16 + c];
#pragma unroll
        for (int k = 0; k < 16; ++k)
            s = fmaf(d2_bo[k], val_wqkv[mat * 256 + k * 16 + c], s);
        bfv[u] = s;
    }
}

// ---------------------------------------------------------------------------
// K1: build f = [r1_bcast | r2_bcast | edge] on the fly and compute
//     qkv1[mat][row][col] = f_row @ d1_wqkv[mat] + d1_bqkv[mat]
// ---------------------------------------------------------------------------
__global__ void qkv1_kernel(const float* __restrict__ r1, const float* __restrict__ r2,
                            const float* __restrict__ edge,
                            const float* __restrict__ wqkv, const float* __restrict__ bqkv,
                            float* __restrict__ qkv1,
                            int B, int M, int F) {
    const int N = M * M;
    const int BN = B * N;
    const int total = 3 * BN * 48;
    int t = blockIdx.x * blockDim.x + threadIdx.x;
    if (t >= total) return;
    int col = t % 48;
    int row = (t / 48) % BN;
    int mat = t / (48 * BN);
    int b = row / N, n = row % N;
    int i = n / M, j = n % M;

    const float* f1 = r1 + (b * M + i) * F;
    const float* f2 = r2 + (b * M + j) * F;
    const float* fe = edge + (size_t)row * F;
    const float* w  = wqkv + mat * 48 * 48 + col;

    float s = bqkv[mat * 48 + col];
#pragma unroll
    for (int d = 0; d < 16; ++d) s = fmaf(f1[d], w[d * 48], s);
#pragma unroll
    for (int d = 0; d < 16; ++d) s = fmaf(f2[d], w[(16 + d) * 48], s);
#pragma unroll
    for (int d = 0; d < 16; ++d) s = fmaf(fe[d], w[(32 + d) * 48], s);
    qkv1[t] = s;
}

// ---------------------------------------------------------------------------
// Build a 16x16x16 MFMA fragment (4 f16, k = 4*lg + j) from a global f32 row,
// zero-padded past DH, scaled by mul.
// ---------------------------------------------------------------------------
template <int DH>
__device__ inline f16x4 load_frag4(const float* __restrict__ base, int lg, float mul) {
    f16x4 r;
    if (4 * lg < DH) {
        float4 v = *(const float4*)(base + 4 * lg);
        r[0] = (f16)(v.x * mul); r[1] = (f16)(v.y * mul);
        r[2] = (f16)(v.z * mul); r[3] = (f16)(v.w * mul);
    } else {
        r[0] = (f16)0.f; r[1] = (f16)0.f; r[2] = (f16)0.f; r[3] = (f16)0.f;
    }
    return r;
}

// ---------------------------------------------------------------------------
// LDS-staged MFMA flash attention partial (see R10). QT q-tiles per wave.
// Block = 4 waves x QT*16 queries, one (b,h), one 256-key chunk.
// gridDim.z MUST equal N/256; gridDim.y = N/(QT*64).
// ---------------------------------------------------------------------------
template <int DH, int QT>
__global__ __launch_bounds__(256, 8) void attn_lds_kernel(
    const float* __restrict__ q1, const float* __restrict__ k1, const float* __restrict__ v1,
    const float* __restrict__ q2, const float* __restrict__ k2, const float* __restrict__ v2,
    const int* __restrict__ mask,
    float* __restrict__ pacc1, float* __restrict__ pl1,
    float* __restrict__ pacc2, float* __restrict__ pl2,
    int B, int H, int N, float qmul) {
    const int LD = H * DH;
    const int BH = B * H;

    int bhs = blockIdx.x;
    const float* qg; const float* kg; const float* vg;
    float* pacc; float* pl;
    if (bhs < BH) { qg = q1; kg = k1; vg = v1; pacc = pacc1; pl = pl1; }
    else          { qg = q2; kg = k2; vg = v2; pacc = pacc2; pl = pl2; bhs -= BH; }
    int b = bhs / H, h = bhs % H;
    int kbase = blockIdx.z * 256;
    int bN = b * N;

    __shared__ __align__(16) f16 Kt[256][DH];   // K rows f16 (tail over-read benign)
    __shared__ __align__(16) f16 Vt[16][264];   // V^T rows 0..DH-1, ones row DH, zero rest
    __shared__ __align__(16) float mbs[256];    // mask bias (log2 domain, incl -8 shift)

    int tid = threadIdx.x;
    for (int i = tid; i < (15 - DH) * 132; i += 256)
        ((int*)Vt)[(DH + 1) * 132 + i] = 0;
    {
        int kk = tid;
        size_t g = ((size_t)(bN + kbase + kk)) * LD + h * DH;
        const float* krow = kg + g;
        const float* vrow = vg + g;
#pragma unroll
        for (int d = 0; d < DH; ++d) {
            Kt[kk][d] = (f16)krow[d];
            Vt[d][kk] = (f16)vrow[d];
        }
        Vt[DH][kk] = (f16)1.f;
        mbs[kk] = mask[bN + kbase + kk] ? (-8.f * LOG2E) : NEGV;
    }
    __syncthreads();

    int lane = tid & 63, wid = tid >> 6;
    int lrow = lane & 15, lg = lane >> 4;
    int qbase = blockIdx.y * (QT * 64) + wid * (QT * 16);

    f16x4 qf[QT];
#pragma unroll
    for (int qt = 0; qt < QT; ++qt)
        qf[qt] = load_frag4<DH>(qg + ((size_t)(bN + qbase + qt * 16 + lrow)) * LD + h * DH, lg, qmul);

    f32x4 oacc[QT];
#pragma unroll
    for (int qt = 0; qt < QT; ++qt) oacc[qt] = (f32x4){0.f, 0.f, 0.f, 0.f};

#pragma unroll 4
    for (int t16 = 0; t16 < 16; ++t16) {
        f16x4 kf = *(const f16x4*)(&Kt[0][0] + (size_t)(t16 * 16 + lrow) * DH + 4 * lg);
        float4 mv = *(const float4*)(&mbs[t16 * 16 + 4 * lg]);
        f32x4 mc = {mv.x, mv.y, mv.z, mv.w};
        f16x4 vb = *(const f16x4*)(&Vt[lrow][t16 * 16 + 4 * lg]);

#pragma unroll
        for (int qt = 0; qt < QT; ++qt) {
            f32x4 s = __builtin_amdgcn_mfma_f32_16x16x16f16(kf, qf[qt], mc, 0, 0, 0);
            hf2 lo = __builtin_amdgcn_cvt_pkrtz(__builtin_amdgcn_exp2f(s[0]),
                                                __builtin_amdgcn_exp2f(s[1]));
            hf2 hi = __builtin_amdgcn_cvt_pkrtz(__builtin_amdgcn_exp2f(s[2]),
                                                __builtin_amdgcn_exp2f(s[3]));
            f16x4 pa;
            ((hf2*)&pa)[0] = lo;
            ((hf2*)&pa)[1] = hi;
            oacc[qt] = __builtin_amdgcn_mfma_f32_16x16x16f16(pa, vb, oacc[qt], 0, 0, 0);
        }
    }

    int d = lrow;
    size_t zoff = (size_t)blockIdx.z * B * N;
#pragma unroll
    for (int qt = 0; qt < QT; ++qt) {
#pragma unroll
        for (int r = 0; r < 4; ++r) {
            int q = qbase + qt * 16 + lg * 4 + r;
            float val = oacc[qt][r];
            if (d < DH)
                pacc[(zoff + bN + q) * LD + h * DH + d] = val;
            else if (d == DH)
                pl[(zoff + bN + q) * H + h] = val;
        }
    }
}

// ---------------------------------------------------------------------------
// fold1: d1 partials -> combine -> @Wf1 -> qkv2[3][BN][16]. 16 rows/block.
// ---------------------------------------------------------------------------
__global__ __launch_bounds__(256) void fold1_kernel(
    const float* __restrict__ pacc, const float* __restrict__ pl,
    const float* __restrict__ Wf1, const float* __restrict__ bf1,
    float* __restrict__ qkv2, int BN) {
    int row0 = blockIdx.x * 16;
    int tid = threadIdx.x;
    __shared__ float comb[16][49];
    __shared__ float invl[16][4];
    if (tid < 64) {
        int r = tid >> 2, h = tid & 3;
        float ls = 0.f;
#pragma unroll
        for (int z = 0; z < 4; ++z) ls += pl[((size_t)z * BN + row0 + r) * 4 + h];
        invl[r][h] = 1.f / ls;
    }
    __syncthreads();
#pragma unroll
    for (int k = 0; k < 3; ++k) {      // 768 = 16 rows x 48 d
        int idx = tid + k * 256;
        int r = idx / 48, d = idx % 48;
        float a = 0.f;
#pragma unroll
        for (int z = 0; z < 4; ++z) a += pacc[((size_t)z * BN + row0 + r) * 48 + d];
        comb[r][d] = a * invl[r][d / 12];
    }
    __syncthreads();
#pragma unroll
    for (int k = 0; k < 3; ++k) {      // 768 = 3 mats x 16 rows x 16 c
        int idx = tid + k * 256;
        int mat = idx / 256, r = (idx % 256) / 16, c = idx % 16;
        float s = bf1[mat * 16 + c];
        const float* wcol = Wf1 + mat * 768 + c;
#pragma unroll
        for (int d = 0; d < 48; ++d)
            s = fmaf(comb[r][d], wcol[d * 16], s);
        qkv2[((size_t)mat * BN + row0 + r) * 16 + c] = s;
    }
}

// ---------------------------------------------------------------------------
// fold2: d2 partials -> combine -> @Wfp/@Wfv -> qkvp, qkvv. 8 rows/block.
// ---------------------------------------------------------------------------
__global__ __launch_bounds__(256) void fold2_kernel(
    const float* __restrict__ pacc, const float* __restrict__ pl,
    const float* __restrict__ Wfp, const float* __restrict__ bfp,
    const float* __restrict__ Wfv, const float* __restrict__ bfv,
    float* __restrict__ qkvp, float* __restrict__ qkvv, int BN) {
    int row0 = blockIdx.x * 8;
    int tid = threadIdx.x;
    __shared__ float comb[8][17];
    __shared__ float invl[8][4];
    if (tid < 32) {
        int r = tid >> 2, h = tid & 3;
        float ls = 0.f;
#pragma unroll
        for (int z = 0; z < 4; ++z) ls += pl[((size_t)z * BN + row0 + r) * 4 + h];
        invl[r][h] = 1.f / ls;
    }
    __syncthreads();
    if (tid < 128) {                   // 8 rows x 16 d
        int r = tid / 16, d = tid % 16;
        float a = 0.f;
#pragma unroll
        for (int z = 0; z < 4; ++z) a += pacc[((size_t)z * BN + row0 + r) * 16 + d];
        comb[r][d] = a * invl[r][d >> 2];
    }
    __syncthreads();
#pragma unroll
    for (int k = 0; k < 3; ++k) {      // 768 = 2 sets x 3 mats x 8 rows x 16 c
        int idx = tid + k * 256;
        int set = idx / 384;
        int rem = idx % 384;
        int mat = rem / 128, r = (rem % 128) / 16, c = rem % 16;
        const float* W  = set ? Wfv : Wfp;
        const float* bb = set ? bfv : bfp;
        float* q        = set ? qkvv : qkvp;
        float s = bb[mat * 16 + c];
        const float* wcol = W + mat * 256 + c;
#pragma unroll
        for (int d = 0; d < 16; ++d)
            s = fmaf(comb[r][d], wcol[d * 16], s);
        q[((size_t)mat * BN + row0 + r) * 16 + c] = s;
    }
}

// ---------------------------------------------------------------------------
// Fused pol/val combine + 16->1 head projections.
// ---------------------------------------------------------------------------
__global__ void heads_fused_kernel(const float* __restrict__ paccp, const float* __restrict__ plp,
                                   const float* __restrict__ paccv, const float* __restrict__ plv,
                                   const float* __restrict__ pol_wo, const float* __restrict__ pol_bo,
                                   const float* __restrict__ val_wo, const float* __restrict__ val_bo,
                                   float* __restrict__ act_raw, float* __restrict__ crit_raw,
                                   int BN, int ksplit) {
    int row = blockIdx.x * blockDim.x + threadIdx.x;
    if (row >= BN) return;

    float sa = pol_bo[0];
    {
        float ls[4] = {0.f, 0.f, 0.f, 0.f};
        for (int z = 0; z < ksplit; ++z) {
            const float* plr = plp + ((size_t)z * BN + row) * 4;
            ls[0] += plr[0]; ls[1] += plr[1]; ls[2] += plr[2]; ls[3] += plr[3];
        }
#pragma unroll
        for (int d = 0; d < 16; ++d) {
            float a = 0.f;
            for (int z = 0; z < ksplit; ++z)
                a += paccp[((size_t)z * BN + row) * 16 + d];
            sa = fmaf(a / ls[d >> 2], pol_wo[d], sa);
        }
    }
    float sc = val_bo[0];
    {
        float ls[4] = {0.f, 0.f, 0.f, 0.f};
        for (int z = 0; z < ksplit; ++z) {
            const float* plr = plv + ((size_t)z * BN + row) * 4;
            ls[0] += plr[0]; ls[1] += plr[1]; ls[2] += plr[2]; ls[3] += plr[3];
        }
#pragma unroll
        for (int d = 0; d < 16; ++d) {
            float a = 0.f;
            for (int z = 0; z < ksplit; ++z)
                a += paccv[((size_t)z * BN + row) * 16 + d];
            sc = fmaf(a / ls[d >> 2], val_wo[d], sc);
        }
    }
    act_raw[row] = sa;
    crit_raw[row] = sc;
}

// ---------------------------------------------------------------------------
// Final: blocks 0..B-1 masked action softmax; blocks B..2B-1 critic matvec.
// ---------------------------------------------------------------------------
__global__ __launch_bounds__(256) void final_kernel(
    const float* __restrict__ act_raw, const int* __restrict__ mask,
    const float* __restrict__ crit_raw, const float* __restrict__ v2w,
    const float* __restrict__ v2b,
    float* __restrict__ out_action, float* __restrict__ out_critic, int N, int B) {
    int tid = threadIdx.x;
    if ((int)blockIdx.x < B) {
        int b = blockIdx.x;
        int lane = tid & 63, wid = tid >> 6;
        __shared__ float wred[4];
        __shared__ float sbcast;

        float local[4];
        float mx = -INFINITY;
#pragma unroll
        for (int i = 0; i < 4; ++i) {
            int n = tid + i * 256;
            float a = act_raw[b * N + n];
            if (mask[b * N + n] == 0) a = NEGV;
            local[i] = a;
            mx = fmaxf(mx, a);
        }
#pragma unroll
        for (int o = 32; o > 0; o >>= 1) mx = fmaxf(mx, __shfl_down(mx, o));
        if (lane == 0) wred[wid] = mx;
        __syncthreads();
        if (tid == 0) sbcast = fmaxf(fmaxf(wred[0], wred[1]), fmaxf(wred[2], wred[3]));
        __syncthreads();
        mx = sbcast;

        float s = 0.f;
#pragma unroll
        for (int i = 0; i < 4; ++i) {
            float p = __expf(local[i] - mx);
            local[i] = p;
            s += p;
        }
#pragma unroll
        for (int o = 32; o > 0; o >>= 1) s += __shfl_down(s, o);
        if (lane == 0) wred[wid] = s;
        __syncthreads();
        if (tid == 0) sbcast = wred[0] + wred[1] + wred[2] + wred[3];
        __syncthreads();
        float inv = 1.f / sbcast;
#pragma unroll
        for (int i = 0; i < 4; ++i) out_action[b * N + tid + i * 256] = local[i] * inv;
    } else {
        int b = blockIdx.x - B;
        int c = tid & 15, seg = tid >> 4;
        __shared__ float red[16][17];
        float s = 0.f;
        int n0 = seg * 64;
        for (int n = n0; n < n0 + 64; ++n)
            s = fmaf(crit_raw[b * N + n], v2w[n * 16 + c], s);
        red[seg][c] = s;
        __syncthreads();
        if (tid < 16) {
            float acc = v2b[tid];
#pragma unroll
            for (int g = 0; g < 16; ++g) acc += red[g][tid];
            out_critic[b * 16 + tid] = acc;
        }
    }
}

// ---------------------------------------------------------------------------
extern "C" void kernel_launch(void* const* d_in, const int* in_sizes, int n_in,
                              void* d_out, int out_size, void* d_ws, size_t ws_size,
                              hipStream_t stream) {
    const int B = 16, M = 32, F = 16, H = 4;
    const int N = M * M;          // 1024
    const int BN = B * N;         // 16384
    const int KSPLIT = 4;         // MUST equal N/256

    const float* r1       = (const float*)d_in[0];
    const float* r2       = (const float*)d_in[1];
    const float* edge     = (const float*)d_in[2];
    const int*   mask     = (const int*)d_in[3];
    const float* d1_wqkv  = (const float*)d_in[4];
    const float* d1_bqkv  = (const float*)d_in[5];
    const float* d1_wo    = (const float*)d_in[6];
    const float* d1_bo    = (const float*)d_in[7];
    const float* d2_wqkv  = (const float*)d_in[8];
    const float* d2_bqkv  = (const float*)d_in[9];
    const float* d2_wo    = (const float*)d_in[10];
    const float* d2_bo    = (const float*)d_in[11];
    const float* pol_wqkv = (const float*)d_in[12];
    const float* pol_bqkv = (const float*)d_in[13];
    const float* pol_wo   = (const float*)d_in[14];
    const float* pol_bo   = (const float*)d_in[15];
    const float* val_wqkv = (const float*)d_in[16];
    const float* val_bqkv = (const float*)d_in[17];
    const float* val_wo   = (const float*)d_in[18];
    const float* val_bo   = (const float*)d_in[19];
    const float* v2_w     = (const float*)d_in[20];
    const float* v2_b     = (const float*)d_in[21];

    float* ws = (float*)d_ws;
    float* qkv1     = ws;                           // 3*BN*48
    float* scr_pacc = qkv1 + 3 * BN * 48;           // 4*BN*48 (max)
    float* scr_pl   = scr_pacc + 4 * BN * 48;       // 8*BN*4
    float* qkv2     = scr_pl + 8 * BN * 4;          // 3*BN*16
    float* araw     = qkv2 + 3 * BN * 16;           // BN
    float* craw     = araw + BN;                    // BN
    float* Wf1      = craw + BN;                    // 2304
    float* bf1      = Wf1 + 2304;                   // 48
    float* Wfp      = bf1 + 48;                     // 768
    float* bfp      = Wfp + 768;                    // 48
    float* Wfv      = bfp + 48;                     // 768
    float* bfv      = Wfv + 768;                    // 48
    // overlays
    float* qkvp  = qkv1;                            // qkv1 dead after d1 attn
    float* qkvv  = qkv1 + 3 * BN * 16;
    float* paccp = scr_pacc;
    float* paccv = scr_pacc + (size_t)KSPLIT * BN * 16;
    float* plp   = scr_pl;
    float* plv   = scr_pl + KSPLIT * BN * H;

    float* out_action = (float*)d_out;              // B*N
    float* out_critic = out_action + BN;            // B*16

    const float qmul1 = (1.0f / sqrtf(12.0f)) * LOG2E;
    const float qmul2 = 0.5f * LOG2E;

    // 1. folded weights (tiny)
    prepw_kernel<<<16, 256, 0, stream>>>(
        d1_wo, d1_bo, d2_wqkv, d2_bqkv, d2_wo, d2_bo,
        pol_wqkv, pol_bqkv, val_wqkv, val_bqkv,
        Wf1, bf1, Wfp, bfp, Wfv, bfv);
    // 2. d1: feature build + QKV
    qkv1_kernel<<<(3 * BN * 48 + 255) / 256, 256, 0, stream>>>(
        r1, r2, edge, d1_wqkv, d1_bqkv, qkv1, B, M, F);
    // 3. d1 attention (QT=4: grid.y = N/256)
    attn_lds_kernel<12, 4><<<dim3(B * H, N / 256, KSPLIT), 256, 0, stream>>>(
        qkv1, qkv1 + BN * 48, qkv1 + 2 * BN * 48,
        qkv1, qkv1 + BN * 48, qkv1 + 2 * BN * 48,
        mask, scr_pacc, scr_pl, scr_pacc, scr_pl, B, H, N, qmul1);
    // 4. fold1: combine + (wo@wqkv) -> qkv2
    fold1_kernel<<<BN / 16, 256, 0, stream>>>(
        scr_pacc, scr_pl, Wf1, bf1, qkv2, BN);
    // 5. d2 attention
    attn_lds_kernel<4, 4><<<dim3(B * H, N / 256, KSPLIT), 256, 0, stream>>>(
        qkv2, qkv2 + BN * 16, qkv2 + 2 * BN * 16,
        qkv2, qkv2 + BN * 16, qkv2 + 2 * BN * 16,
        mask, scr_pacc, scr_pl, scr_pacc, scr_pl, B, H, N, qmul2);
    // 6. fold2: combine + folded pol/val qkv
    fold2_kernel<<<BN / 8, 256, 0, stream>>>(
        scr_pacc, scr_pl, Wfp, bfp, Wfv, bfv, qkvp, qkvv, BN);
    // 7. pol + val attention (two sets in one launch)
    attn_lds_kernel<4, 4><<<dim3(2 * B * H, N / 256, KSPLIT), 256, 0, stream>>>(
        qkvp, qkvp + BN * 16, qkvp + 2 * BN * 16,
        qkvv, qkvv + BN * 16, qkvv + 2 * BN * 16,
        mask, paccp, plp, paccv, plv, B, H, N, qmul2);
    // 8. pol/val combine + head projections
    heads_fused_kernel<<<(BN + 255) / 256, 256, 0, stream>>>(
        paccp, plp, paccv, plv, pol_wo, pol_bo, val_wo, val_bo, araw, craw, BN, KSPLIT);
    // 9. masked action softmax + critic
    final_kernel<<<2 * B, 256, 0, stream>>>(
        araw, mask, craw, v2_w, v2_b, out_action, out_critic, N, B);
}

// Round 13
// 146.890 us; speedup vs baseline: 1.0483x; 1.0483x over previous
//
#include <hip/hip_runtime.h>
#include <math.h>

#define NEGV (-1e9f)
#define LOG2E 1.4426950408889634f

typedef _Float16 f16;
typedef __attribute__((ext_vector_type(2))) __fp16 hf2;
typedef __attribute__((ext_vector_type(4))) _Float16 f16x4;
typedef __attribute__((ext_vector_type(4))) float f32x4;

// ---------------------------------------------------------------------------
// Fused: main blocks do qkv1 (feature build + d1 QKV); tail 16 blocks fold
// the affine pairs:
//   Wf1[m](48x16) = d1_wo @ d2_wqkv[m];  bf1[m] = d1_bo@d2_wqkv[m] + d2_bqkv[m]
//   Wfp[m](16x16) = d2_wo @ pol_wqkv[m]; bfp[m] = d2_bo@pol_wqkv[m] + pol_bqkv[m]
//   Wfv[m](16x16) = d2_wo @ val_wqkv[m]; bfv[m] = d2_bo@val_wqkv[m] + val_bqkv[m]
// ---------------------------------------------------------------------------
__global__ void qkv1_prep_kernel(
    const float* __restrict__ r1, const float* __restrict__ r2,
    const float* __restrict__ edge,
    const float* __restrict__ d1_wqkv, const float* __restrict__ d1_bqkv,
    const float* __restrict__ d1_wo, const float* __restrict__ d1_bo,
    const float* __restrict__ d2_wqkv, const float* __restrict__ d2_bqkv,
    const float* __restrict__ d2_wo, const float* __restrict__ d2_bo,
    const float* __restrict__ pol_wqkv, const float* __restrict__ pol_bqkv,
    const float* __restrict__ val_wqkv, const float* __restrict__ val_bqkv,
    float* __restrict__ qkv1,
    float* __restrict__ Wf1, float* __restrict__ bf1,
    float* __restrict__ Wfp, float* __restrict__ bfp,
    float* __restrict__ Wfv, float* __restrict__ bfv,
    int B, int M, int F, int mainBlocks) {
    const int N = M * M;
    const int BN = B * N;

    if ((int)blockIdx.x < mainBlocks) {
        int t = blockIdx.x * blockDim.x + threadIdx.x;
        if (t >= 3 * BN * 48) return;
        int col = t % 48;
        int row = (t / 48) % BN;
        int mat = t / (48 * BN);
        int b = row / N, n = row % N;
        int i = n / M, j = n % M;

        const float* f1 = r1 + (b * M + i) * F;
        const float* f2 = r2 + (b * M + j) * F;
        const float* fe = edge + (size_t)row * F;
        const float* w  = d1_wqkv + mat * 48 * 48 + col;

        float s = d1_bqkv[mat * 48 + col];
#pragma unroll
        for (int d = 0; d < 16; ++d) s = fmaf(f1[d], w[d * 48], s);
#pragma unroll
        for (int d = 0; d < 16; ++d) s = fmaf(f2[d], w[(16 + d) * 48], s);
#pragma unroll
        for (int d = 0; d < 16; ++d) s = fmaf(fe[d], w[(32 + d) * 48], s);
        qkv1[t] = s;
        return;
    }

    // prep path
    int t = (blockIdx.x - mainBlocks) * blockDim.x + threadIdx.x;
    if (t < 2304) {                     // Wf1
        int mat = t / 768, r = (t % 768) / 16, c = t % 16;
        float s = 0.f;
#pragma unroll
        for (int k = 0; k < 16; ++k)
            s = fmaf(d1_wo[r * 16 + k], d2_wqkv[mat * 256 + k * 16 + c], s);
        Wf1[t] = s;
        return;
    }
    int u = t - 2304;
    if (u < 48) {                       // bf1
        int mat = u / 16, c = u % 16;
        float s = d2_bqkv[mat * 16 + c];
#pragma unroll
        for (int k = 0; k < 16; ++k)
            s = fmaf(d1_bo[k], d2_wqkv[mat * 256 + k * 16 + c], s);
        bf1[u] = s;
        return;
    }
    u -= 48;
    if (u < 768) {                      // Wfp
        int mat = u / 256, r = (u % 256) / 16, c = u % 16;
        float s = 0.f;
#pragma unroll
        for (int k = 0; k < 16; ++k)
            s = fmaf(d2_wo[r * 16 + k], pol_wqkv[mat * 256 + k * 16 + c], s);
        Wfp[u] = s;
        return;
    }
    u -= 768;
    if (u < 48) {                       // bfp
        int mat = u / 16, c = u % 16;
        float s = pol_bqkv[mat * 16 + c];
#pragma unroll
        for (int k = 0; k < 16; ++k)
            s = fmaf(d2_bo[k], pol_wqkv[mat * 256 + k * 16 + c], s);
        bfp[u] = s;
        return;
    }
    u -= 48;
    if (u < 768) {                      // Wfv
        int mat = u / 256, r = (u % 256) / 16, c = u % 16;
        float s = 0.f;
#pragma unroll
        for (int k = 0; k < 16; ++k)
            s = fmaf(d2_wo[r * 16 + k], val_wqkv[mat * 256 + k * 16 + c], s);
        Wfv[u] = s;
        return;
    }
    u -= 768;
    if (u < 48) {                       // bfv
        int mat = u / 16, c = u % 16;
        float s = val_bqkv[mat * 16 + c];
#pragma unroll
        for (int k = 0; k < 16; ++k)
            s = fmaf(d2_bo[k], val_wqkv[mat * 256 + k * 16 + c], s);
        bfv[u] = s;
    }
}

// ---------------------------------------------------------------------------
// Build a 16x16x16 MFMA fragment (4 f16, k = 4*lg + j) from a global f32 row,
// zero-padded past DH, scaled by mul.
// ---------------------------------------------------------------------------
template <int DH>
__device__ inline f16x4 load_frag4(const float* __restrict__ base, int lg, float mul) {
    f16x4 r;
    if (4 * lg < DH) {
        float4 v = *(const float4*)(base + 4 * lg);
        r[0] = (f16)(v.x * mul); r[1] = (f16)(v.y * mul);
        r[2] = (f16)(v.z * mul); r[3] = (f16)(v.w * mul);
    } else {
        r[0] = (f16)0.f; r[1] = (f16)0.f; r[2] = (f16)0.f; r[3] = (f16)0.f;
    }
    return r;
}

// ---------------------------------------------------------------------------
// LDS-staged MFMA flash attention partial. QT q-tiles per wave.
// Vt rows > DH are uninitialized garbage: they only affect output columns
// (lrow > DH) that the epilogue discards.
// Block = 4 waves x QT*16 queries, one (b,h), one 256-key chunk.
// gridDim.z MUST equal N/256; gridDim.y = N/(QT*64).
// ---------------------------------------------------------------------------
template <int DH, int QT>
__global__ __launch_bounds__(256, 8) void attn_lds_kernel(
    const float* __restrict__ q1, const float* __restrict__ k1, const float* __restrict__ v1,
    const float* __restrict__ q2, const float* __restrict__ k2, const float* __restrict__ v2,
    const int* __restrict__ mask,
    float* __restrict__ pacc1, float* __restrict__ pl1,
    float* __restrict__ pacc2, float* __restrict__ pl2,
    int B, int H, int N, float qmul) {
    const int LD = H * DH;
    const int BH = B * H;

    int bhs = blockIdx.x;
    const float* qg; const float* kg; const float* vg;
    float* pacc; float* pl;
    if (bhs < BH) { qg = q1; kg = k1; vg = v1; pacc = pacc1; pl = pl1; }
    else          { qg = q2; kg = k2; vg = v2; pacc = pacc2; pl = pl2; bhs -= BH; }
    int b = bhs / H, h = bhs % H;
    int kbase = blockIdx.z * 256;
    int bN = b * N;

    __shared__ __align__(16) f16 Kt[256][DH];   // K rows f16 (tail over-read benign)
    __shared__ __align__(16) f16 Vt[16][264];   // V^T rows 0..DH-1, ones row DH; rest garbage
    __shared__ __align__(16) float mbs[256];    // mask bias (log2 domain, incl -8 shift)

    int tid = threadIdx.x;
    {
        int kk = tid;
        size_t g = ((size_t)(bN + kbase + kk)) * LD + h * DH;
        const float* krow = kg + g;
        const float* vrow = vg + g;
#pragma unroll
        for (int d = 0; d < DH; ++d) {
            Kt[kk][d] = (f16)krow[d];
            Vt[d][kk] = (f16)vrow[d];
        }
        Vt[DH][kk] = (f16)1.f;
        mbs[kk] = mask[bN + kbase + kk] ? (-8.f * LOG2E) : NEGV;
    }
    __syncthreads();

    int lane = tid & 63, wid = tid >> 6;
    int lrow = lane & 15, lg = lane >> 4;
    int qbase = blockIdx.y * (QT * 64) + wid * (QT * 16);

    f16x4 qf[QT];
#pragma unroll
    for (int qt = 0; qt < QT; ++qt)
        qf[qt] = load_frag4<DH>(qg + ((size_t)(bN + qbase + qt * 16 + lrow)) * LD + h * DH, lg, qmul);

    f32x4 oacc[QT];
#pragma unroll
    for (int qt = 0; qt < QT; ++qt) oacc[qt] = (f32x4){0.f, 0.f, 0.f, 0.f};

#pragma unroll 8
    for (int t16 = 0; t16 < 16; ++t16) {
        f16x4 kf = *(const f16x4*)(&Kt[0][0] + (size_t)(t16 * 16 + lrow) * DH + 4 * lg);
        float4 mv = *(const float4*)(&mbs[t16 * 16 + 4 * lg]);
        f32x4 mc = {mv.x, mv.y, mv.z, mv.w};
        f16x4 vb = *(const f16x4*)(&Vt[lrow][t16 * 16 + 4 * lg]);

#pragma unroll
        for (int qt = 0; qt < QT; ++qt) {
            f32x4 s = __builtin_amdgcn_mfma_f32_16x16x16f16(kf, qf[qt], mc, 0, 0, 0);
            hf2 lo = __builtin_amdgcn_cvt_pkrtz(__builtin_amdgcn_exp2f(s[0]),
                                                __builtin_amdgcn_exp2f(s[1]));
            hf2 hi = __builtin_amdgcn_cvt_pkrtz(__builtin_amdgcn_exp2f(s[2]),
                                                __builtin_amdgcn_exp2f(s[3]));
            f16x4 pa;
            ((hf2*)&pa)[0] = lo;
            ((hf2*)&pa)[1] = hi;
            oacc[qt] = __builtin_amdgcn_mfma_f32_16x16x16f16(pa, vb, oacc[qt], 0, 0, 0);
        }
    }

    int d = lrow;
    size_t zoff = (size_t)blockIdx.z * B * N;
#pragma unroll
    for (int qt = 0; qt < QT; ++qt) {
#pragma unroll
        for (int r = 0; r < 4; ++r) {
            int q = qbase + qt * 16 + lg * 4 + r;
            float val = oacc[qt][r];
            if (d < DH)
                pacc[(zoff + bN + q) * LD + h * DH + d] = val;
            else if (d == DH)
                pl[(zoff + bN + q) * H + h] = val;
        }
    }
}

// ---------------------------------------------------------------------------
// fold1: d1 partials -> combine -> @Wf1 -> qkv2[3][BN][16]. 16 rows/block.
// ---------------------------------------------------------------------------
__global__ __launch_bounds__(256) void fold1_kernel(
    const float* __restrict__ pacc, const float* __restrict__ pl,
    const float* __restrict__ Wf1, const float* __restrict__ bf1,
    float* __restrict__ qkv2, int BN) {
    int row0 = blockIdx.x * 16;
    int tid = threadIdx.x;
    __shared__ float comb[16][49];
    __shared__ float invl[16][4];
    if (tid < 64) {
        int r = tid >> 2, h = tid & 3;
        float ls = 0.f;
#pragma unroll
        for (int z = 0; z < 4; ++z) ls += pl[((size_t)z * BN + row0 + r) * 4 + h];
        invl[r][h] = 1.f / ls;
    }
    __syncthreads();
#pragma unroll
    for (int k = 0; k < 3; ++k) {      // 768 = 16 rows x 48 d
        int idx = tid + k * 256;
        int r = idx / 48, d = idx % 48;
        float a = 0.f;
#pragma unroll
        for (int z = 0; z < 4; ++z) a += pacc[((size_t)z * BN + row0 + r) * 48 + d];
        comb[r][d] = a * invl[r][d / 12];
    }
    __syncthreads();
#pragma unroll
    for (int k = 0; k < 3; ++k) {      // 768 = 3 mats x 16 rows x 16 c
        int idx = tid + k * 256;
        int mat = idx / 256, r = (idx % 256) / 16, c = idx % 16;
        float s = bf1[mat * 16 + c];
        const float* wcol = Wf1 + mat * 768 + c;
#pragma unroll
        for (int d = 0; d < 48; ++d)
            s = fmaf(comb[r][d], wcol[d * 16], s);
        qkv2[((size_t)mat * BN + row0 + r) * 16 + c] = s;
    }
}

// ---------------------------------------------------------------------------
// fold2: d2 partials -> combine -> @Wfp/@Wfv -> qkvp, qkvv. 8 rows/block.
// ---------------------------------------------------------------------------
__global__ __launch_bounds__(256) void fold2_kernel(
    const float* __restrict__ pacc, const float* __restrict__ pl,
    const float* __restrict__ Wfp, const float* __restrict__ bfp,
    const float* __restrict__ Wfv, const float* __restrict__ bfv,
    float* __restrict__ qkvp, float* __restrict__ qkvv, int BN) {
    int row0 = blockIdx.x * 8;
    int tid = threadIdx.x;
    __shared__ float comb[8][17];
    __shared__ float invl[8][4];
    if (tid < 32) {
        int r = tid >> 2, h = tid & 3;
        float ls = 0.f;
#pragma unroll
        for (int z = 0; z < 4; ++z) ls += pl[((size_t)z * BN + row0 + r) * 4 + h];
        invl[r][h] = 1.f / ls;
    }
    __syncthreads();
    if (tid < 128) {                   // 8 rows x 16 d
        int r = tid / 16, d = tid % 16;
        float a = 0.f;
#pragma unroll
        for (int z = 0; z < 4; ++z) a += pacc[((size_t)z * BN + row0 + r) * 16 + d];
        comb[r][d] = a * invl[r][d >> 2];
    }
    __syncthreads();
#pragma unroll
    for (int k = 0; k < 3; ++k) {      // 768 = 2 sets x 3 mats x 8 rows x 16 c
        int idx = tid + k * 256;
        int set = idx / 384;
        int rem = idx % 384;
        int mat = rem / 128, r = (rem % 128) / 16, c = rem % 16;
        const float* W  = set ? Wfv : Wfp;
        const float* bb = set ? bfv : bfp;
        float* q        = set ? qkvv : qkvp;
        float s = bb[mat * 16 + c];
        const float* wcol = W + mat * 256 + c;
#pragma unroll
        for (int d = 0; d < 16; ++d)
            s = fmaf(comb[r][d], wcol[d * 16], s);
        q[((size_t)mat * BN + row0 + r) * 16 + c] = s;
    }
}

// ---------------------------------------------------------------------------
// Fused pol/val combine + 16->1 head projections.
// ---------------------------------------------------------------------------
__global__ void heads_fused_kernel(const float* __restrict__ paccp, const float* __restrict__ plp,
                                   const float* __restrict__ paccv, const float* __restrict__ plv,
                                   const float* __restrict__ pol_wo, const float* __restrict__ pol_bo,
                                   const float* __restrict__ val_wo, const float* __restrict__ val_bo,
                                   float* __restrict__ act_raw, float* __restrict__ crit_raw,
                                   int BN, int ksplit) {
    int row = blockIdx.x * blockDim.x + threadIdx.x;
    if (row >= BN) return;

    float sa = pol_bo[0];
    {
        float ls[4] = {0.f, 0.f, 0.f, 0.f};
        for (int z = 0; z < ksplit; ++z) {
            const float* plr = plp + ((size_t)z * BN + row) * 4;
            ls[0] += plr[0]; ls[1] += plr[1]; ls[2] += plr[2]; ls[3] += plr[3];
        }
#pragma unroll
        for (int d = 0; d < 16; ++d) {
            float a = 0.f;
            for (int z = 0; z < ksplit; ++z)
                a += paccp[((size_t)z * BN + row) * 16 + d];
            sa = fmaf(a / ls[d >> 2], pol_wo[d], sa);
        }
    }
    float sc = val_bo[0];
    {
        float ls[4] = {0.f, 0.f, 0.f, 0.f};
        for (int z = 0; z < ksplit; ++z) {
            const float* plr = plv + ((size_t)z * BN + row) * 4;
            ls[0] += plr[0]; ls[1] += plr[1]; ls[2] += plr[2]; ls[3] += plr[3];
        }
#pragma unroll
        for (int d = 0; d < 16; ++d) {
            float a = 0.f;
            for (int z = 0; z < ksplit; ++z)
                a += paccv[((size_t)z * BN + row) * 16 + d];
            sc = fmaf(a / ls[d >> 2], val_wo[d], sc);
        }
    }
    act_raw[row] = sa;
    crit_raw[row] = sc;
}

// ---------------------------------------------------------------------------
// Final: blocks 0..B-1 masked action softmax; blocks B..2B-1 critic matvec.
// ---------------------------------------------------------------------------
__global__ __launch_bounds__(256) void final_kernel(
    const float* __restrict__ act_raw, const int* __restrict__ mask,
    const float* __restrict__ crit_raw, const float* __restrict__ v2w,
    const float* __restrict__ v2b,
    float* __restrict__ out_action, float* __restrict__ out_critic, int N, int B) {
    int tid = threadIdx.x;
    if ((int)blockIdx.x < B) {
        int b = blockIdx.x;
        int lane = tid & 63, wid = tid >> 6;
        __shared__ float wred[4];
        __shared__ float sbcast;

        float local[4];
        float mx = -INFINITY;
#pragma unroll
        for (int i = 0; i < 4; ++i) {
            int n = tid + i * 256;
            float a = act_raw[b * N + n];
            if (mask[b * N + n] == 0) a = NEGV;
            local[i] = a;
            mx = fmaxf(mx, a);
        }
#pragma unroll
        for (int o = 32; o > 0; o >>= 1) mx = fmaxf(mx, __shfl_down(mx, o));
        if (lane == 0) wred[wid] = mx;
        __syncthreads();
        if (tid == 0) sbcast = fmaxf(fmaxf(wred[0], wred[1]), fmaxf(wred[2], wred[3]));
        __syncthreads();
        mx = sbcast;

        float s = 0.f;
#pragma unroll
        for (int i = 0; i < 4; ++i) {
            float p = __expf(local[i] - mx);
            local[i] = p;
            s += p;
        }
#pragma unroll
        for (int o = 32; o > 0; o >>= 1) s += __shfl_down(s, o);
        if (lane == 0) wred[wid] = s;
        __syncthreads();
        if (tid == 0) sbcast = wred[0] + wred[1] + wred[2] + wred[3];
        __syncthreads();
        float inv = 1.f / sbcast;
#pragma unroll
        for (int i = 0; i < 4; ++i) out_action[b * N + tid + i * 256] = local[i] * inv;
    } else {
        int b = blockIdx.x - B;
        int c = tid & 15, seg = tid >> 4;
        __shared__ float red[16][17];
        float s = 0.f;
        int n0 = seg * 64;
        for (int n = n0; n < n0 + 64; ++n)
            s = fmaf(crit_raw[b * N + n], v2w[n * 16 + c], s);
        red[seg][c] = s;
        __syncthreads();
        if (tid < 16) {
            float acc = v2b[tid];
#pragma unroll
            for (int g = 0; g < 16; ++g) acc += red[g][tid];
            out_critic[b * 16 + tid] = acc;
        }
    }
}

// ---------------------------------------------------------------------------
extern "C" void kernel_launch(void* const* d_in, const int* in_sizes, int n_in,
                              void* d_out, int out_size, void* d_ws, size_t ws_size,
                              hipStream_t stream) {
    const int B = 16, M = 32, F = 16, H = 4;
    const int N = M * M;          // 1024
    const int BN = B * N;         // 16384
    const int KSPLIT = 4;         // MUST equal N/256

    const float* r1       = (const float*)d_in[0];
    const float* r2       = (const float*)d_in[1];
    const float* edge     = (const float*)d_in[2];
    const int*   mask     = (const int*)d_in[3];
    const float* d1_wqkv  = (const float*)d_in[4];
    const float* d1_bqkv  = (const float*)d_in[5];
    const float* d1_wo    = (const float*)d_in[6];
    const float* d1_bo    = (const float*)d_in[7];
    const float* d2_wqkv  = (const float*)d_in[8];
    const float* d2_bqkv  = (const float*)d_in[9];
    const float* d2_wo    = (const float*)d_in[10];
    const float* d2_bo    = (const float*)d_in[11];
    const float* pol_wqkv = (const float*)d_in[12];
    const float* pol_bqkv = (const float*)d_in[13];
    const float* pol_wo   = (const float*)d_in[14];
    const float* pol_bo   = (const float*)d_in[15];
    const float* val_wqkv = (const float*)d_in[16];
    const float* val_bqkv = (const float*)d_in[17];
    const float* val_wo   = (const float*)d_in[18];
    const float* val_bo   = (const float*)d_in[19];
    const float* v2_w     = (const float*)d_in[20];
    const float* v2_b     = (const float*)d_in[21];

    float* ws = (float*)d_ws;
    float* qkv1     = ws;                           // 3*BN*48
    float* scr_pacc = qkv1 + 3 * BN * 48;           // 4*BN*48 (max)
    float* scr_pl   = scr_pacc + 4 * BN * 48;       // 8*BN*4
    float* qkv2     = scr_pl + 8 * BN * 4;          // 3*BN*16
    float* araw     = qkv2 + 3 * BN * 16;           // BN
    float* craw     = araw + BN;                    // BN
    float* Wf1      = craw + BN;                    // 2304
    float* bf1      = Wf1 + 2304;                   // 48
    float* Wfp      = bf1 + 48;                     // 768
    float* bfp      = Wfp + 768;                    // 48
    float* Wfv      = bfp + 48;                     // 768
    float* bfv      = Wfv + 768;                    // 48
    // overlays
    float* qkvp  = qkv1;                            // qkv1 dead after d1 attn
    float* qkvv  = qkv1 + 3 * BN * 16;
    float* paccp = scr_pacc;
    float* paccv = scr_pacc + (size_t)KSPLIT * BN * 16;
    float* plp   = scr_pl;
    float* plv   = scr_pl + KSPLIT * BN * H;

    float* out_action = (float*)d_out;              // B*N
    float* out_critic = out_action + BN;            // B*16

    const float qmul1 = (1.0f / sqrtf(12.0f)) * LOG2E;
    const float qmul2 = 0.5f * LOG2E;

    // 1. d1 QKV + folded-weight prep (merged launch)
    {
        int mainBlocks = (3 * BN * 48 + 255) / 256;
        qkv1_prep_kernel<<<mainBlocks + 16, 256, 0, stream>>>(
            r1, r2, edge, d1_wqkv, d1_bqkv, d1_wo, d1_bo,
            d2_wqkv, d2_bqkv, d2_wo, d2_bo,
            pol_wqkv, pol_bqkv, val_wqkv, val_bqkv,
            qkv1, Wf1, bf1, Wfp, bfp, Wfv, bfv, B, M, F, mainBlocks);
    }
    // 2. d1 attention (QT=2: grid.y = N/128 -> full occupancy)
    attn_lds_kernel<12, 2><<<dim3(B * H, N / 128, KSPLIT), 256, 0, stream>>>(
        qkv1, qkv1 + BN * 48, qkv1 + 2 * BN * 48,
        qkv1, qkv1 + BN * 48, qkv1 + 2 * BN * 48,
        mask, scr_pacc, scr_pl, scr_pacc, scr_pl, B, H, N, qmul1);
    // 3. fold1: combine + (wo@wqkv) -> qkv2
    fold1_kernel<<<BN / 16, 256, 0, stream>>>(
        scr_pacc, scr_pl, Wf1, bf1, qkv2, BN);
    // 4. d2 attention
    attn_lds_kernel<4, 2><<<dim3(B * H, N / 128, KSPLIT), 256, 0, stream>>>(
        qkv2, qkv2 + BN * 16, qkv2 + 2 * BN * 16,
        qkv2, qkv2 + BN * 16, qkv2 + 2 * BN * 16,
        mask, scr_pacc, scr_pl, scr_pacc, scr_pl, B, H, N, qmul2);
    // 5. fold2: combine + folded pol/val qkv
    fold2_kernel<<<BN / 8, 256, 0, stream>>>(
        scr_pacc, scr_pl, Wfp, bfp, Wfv, bfv, qkvp, qkvv, BN);
    // 6. pol + val attention (two sets in one launch)
    attn_lds_kernel<4, 2><<<dim3(2 * B * H, N / 128, KSPLIT), 256, 0, stream>>>(
        qkvp, qkvp + BN * 16, qkvp + 2 * BN * 16,
        qkvv, qkvv + BN * 16, qkvv + 2 * BN * 16,
        mask, paccp, plp, paccv, plv, B, H, N, qmul2);
    // 7. pol/val combine + head projections
    heads_fused_kernel<<<(BN + 255) / 256, 256, 0, stream>>>(
        paccp, plp, paccv, plv, pol_wo, pol_bo, val_wo, val_bo, araw, craw, BN, KSPLIT);
    // 8. masked action softmax + critic
    final_kernel<<<2 * B, 256, 0, stream>>>(
        araw, mask, craw, v2_w, v2_b, out_action, out_critic, N, B);
}

// Round 14
// 105.008 us; speedup vs baseline: 1.4664x; 1.3989x over previous
//
#include <hip/hip_runtime.h>
#include <math.h>

#define NEGV (-1e9f)
#define LOG2E 1.4426950408889634f

typedef _Float16 f16;
typedef __attribute__((ext_vector_type(2))) __fp16 hf2;
typedef __attribute__((ext_vector_type(4))) _Float16 f16x4;
typedef __attribute__((ext_vector_type(4))) float f32x4;

// ---------------------------------------------------------------------------
// Fused: main blocks build f=[r1|r2|edge], compute d1 QKV and write f16
// head-major Q (pre-scaled by qmul1), K, V: [BH][N][12].
// Tail 16 blocks fold the affine pairs (Wf1/bf1, Wfp/bfp, Wfv/bfv).
// ---------------------------------------------------------------------------
__global__ void qkv1_prep_kernel(
    const float* __restrict__ r1, const float* __restrict__ r2,
    const float* __restrict__ edge,
    const float* __restrict__ d1_wqkv, const float* __restrict__ d1_bqkv,
    const float* __restrict__ d1_wo, const float* __restrict__ d1_bo,
    const float* __restrict__ d2_wqkv, const float* __restrict__ d2_bqkv,
    const float* __restrict__ d2_wo, const float* __restrict__ d2_bo,
    const float* __restrict__ pol_wqkv, const float* __restrict__ pol_bqkv,
    const float* __restrict__ val_wqkv, const float* __restrict__ val_bqkv,
    f16* __restrict__ q1h, f16* __restrict__ k1h, f16* __restrict__ v1h,
    float* __restrict__ Wf1, float* __restrict__ bf1,
    float* __restrict__ Wfp, float* __restrict__ bfp,
    float* __restrict__ Wfv, float* __restrict__ bfv,
    int B, int M, int F, int H, float qmul1, int mainBlocks) {
    const int N = M * M;
    const int BN = B * N;

    if ((int)blockIdx.x < mainBlocks) {
        int t = blockIdx.x * blockDim.x + threadIdx.x;
        if (t >= 3 * BN * 48) return;
        int col = t % 48;
        int row = (t / 48) % BN;
        int mat = t / (48 * BN);
        int b = row / N, n = row % N;
        int i = n / M, j = n % M;

        const float* f1 = r1 + (b * M + i) * F;
        const float* f2 = r2 + (b * M + j) * F;
        const float* fe = edge + (size_t)row * F;
        const float* w  = d1_wqkv + mat * 48 * 48 + col;

        float s = d1_bqkv[mat * 48 + col];
#pragma unroll
        for (int d = 0; d < 16; ++d) s = fmaf(f1[d], w[d * 48], s);
#pragma unroll
        for (int d = 0; d < 16; ++d) s = fmaf(f2[d], w[(16 + d) * 48], s);
#pragma unroll
        for (int d = 0; d < 16; ++d) s = fmaf(fe[d], w[(32 + d) * 48], s);

        int h = col / 12, dd = col % 12;
        size_t off = ((size_t)(b * H + h) * N + n) * 12 + dd;
        if (mat == 0)      q1h[off] = (f16)(s * qmul1);
        else if (mat == 1) k1h[off] = (f16)s;
        else               v1h[off] = (f16)s;
        return;
    }

    // prep path (folded weights)
    int t = (blockIdx.x - mainBlocks) * blockDim.x + threadIdx.x;
    if (t < 2304) {                     // Wf1
        int mat = t / 768, r = (t % 768) / 16, c = t % 16;
        float s = 0.f;
#pragma unroll
        for (int k = 0; k < 16; ++k)
            s = fmaf(d1_wo[r * 16 + k], d2_wqkv[mat * 256 + k * 16 + c], s);
        Wf1[t] = s;
        return;
    }
    int u = t - 2304;
    if (u < 48) {                       // bf1
        int mat = u / 16, c = u % 16;
        float s = d2_bqkv[mat * 16 + c];
#pragma unroll
        for (int k = 0; k < 16; ++k)
            s = fmaf(d1_bo[k], d2_wqkv[mat * 256 + k * 16 + c], s);
        bf1[u] = s;
        return;
    }
    u -= 48;
    if (u < 768) {                      // Wfp
        int mat = u / 256, r = (u % 256) / 16, c = u % 16;
        float s = 0.f;
#pragma unroll
        for (int k = 0; k < 16; ++k)
            s = fmaf(d2_wo[r * 16 + k], pol_wqkv[mat * 256 + k * 16 + c], s);
        Wfp[u] = s;
        return;
    }
    u -= 768;
    if (u < 48) {                       // bfp
        int mat = u / 16, c = u % 16;
        float s = pol_bqkv[mat * 16 + c];
#pragma unroll
        for (int k = 0; k < 16; ++k)
            s = fmaf(d2_bo[k], pol_wqkv[mat * 256 + k * 16 + c], s);
        bfp[u] = s;
        return;
    }
    u -= 48;
    if (u < 768) {                      // Wfv
        int mat = u / 256, r = (u % 256) / 16, c = u % 16;
        float s = 0.f;
#pragma unroll
        for (int k = 0; k < 16; ++k)
            s = fmaf(d2_wo[r * 16 + k], val_wqkv[mat * 256 + k * 16 + c], s);
        Wfv[u] = s;
        return;
    }
    u -= 768;
    if (u < 48) {                       // bfv
        int mat = u / 16, c = u % 16;
        float s = val_bqkv[mat * 16 + c];
#pragma unroll
        for (int k = 0; k < 16; ++k)
            s = fmaf(d2_bo[k], val_wqkv[mat * 256 + k * 16 + c], s);
        bfv[u] = s;
    }
}

// ---------------------------------------------------------------------------
// LDS-staged MFMA flash attention partial, f16 head-major inputs
// ([BH][N][DH], Q pre-scaled by scale*log2e). Staging is pure copy.
// Vt rows > DH are garbage; they only affect discarded output columns.
// K-frag over-read past DH is nullified by zero-padded Q fragments.
// Block = 4 waves x QT*16 queries, one (b,h), one 256-key chunk.
// gridDim.z MUST equal N/256; gridDim.y = N/(QT*64).
// ---------------------------------------------------------------------------
template <int DH, int QT>
__global__ __launch_bounds__(256, 8) void attn_h_kernel(
    const f16* __restrict__ qh1, const f16* __restrict__ kh1, const f16* __restrict__ vh1,
    const f16* __restrict__ qh2, const f16* __restrict__ kh2, const f16* __restrict__ vh2,
    const int* __restrict__ mask,
    float* __restrict__ pacc1, float* __restrict__ pl1,
    float* __restrict__ pacc2, float* __restrict__ pl2,
    int B, int H, int N) {
    const int LD = H * DH;
    const int BH = B * H;

    int bhs = blockIdx.x;
    const f16* qh; const f16* kh; const f16* vh;
    float* pacc; float* pl;
    if (bhs < BH) { qh = qh1; kh = kh1; vh = vh1; pacc = pacc1; pl = pl1; }
    else          { qh = qh2; kh = kh2; vh = vh2; pacc = pacc2; pl = pl2; bhs -= BH; }
    int b = bhs / H, h = bhs % H;
    int kbase = blockIdx.z * 256;
    int bN = b * N;

    __shared__ __align__(16) f16 Kt[256][DH];   // K rows (tail over-read benign)
    __shared__ __align__(16) f16 Vt[16][264];   // V^T rows 0..DH-1, ones row DH; rest garbage
    __shared__ __align__(16) float mbs[256];    // mask bias (log2 domain, incl -8 shift)

    int tid = threadIdx.x;
    {
        int kk = tid;
        const f16* kB = kh + ((size_t)bhs * N + kbase) * DH;
        const f16* vB = vh + ((size_t)bhs * N + kbase) * DH;
        // K: vector copy
#pragma unroll
        for (int d = 0; d < DH / 4; ++d)
            ((uint2*)&Kt[kk][0])[d] = ((const uint2*)(kB + (size_t)kk * DH))[d];
        // V: vector load, transpose-scatter into Vt
        uint2 vr[DH / 4];
#pragma unroll
        for (int d = 0; d < DH / 4; ++d)
            vr[d] = ((const uint2*)(vB + (size_t)kk * DH))[d];
        const f16* vv = (const f16*)vr;
#pragma unroll
        for (int d = 0; d < DH; ++d) Vt[d][kk] = vv[d];
        Vt[DH][kk] = (f16)1.f;
        mbs[kk] = mask[bN + kbase + kk] ? (-8.f * LOG2E) : NEGV;
    }
    __syncthreads();

    int lane = tid & 63, wid = tid >> 6;
    int lrow = lane & 15, lg = lane >> 4;
    int qbase = blockIdx.y * (QT * 64) + wid * (QT * 16);

    const f16* qB = qh + (size_t)bhs * N * DH;
    f16x4 zf = {(f16)0.f, (f16)0.f, (f16)0.f, (f16)0.f};
    bool qok = (4 * lg < DH);
    f16x4 qf[QT];
#pragma unroll
    for (int qt = 0; qt < QT; ++qt)
        qf[qt] = qok ? *(const f16x4*)(qB + (size_t)(qbase + qt * 16 + lrow) * DH + 4 * lg) : zf;

    f32x4 oacc[QT];
#pragma unroll
    for (int qt = 0; qt < QT; ++qt) oacc[qt] = (f32x4){0.f, 0.f, 0.f, 0.f};

#pragma unroll 8
    for (int t16 = 0; t16 < 16; ++t16) {
        f16x4 kf = *(const f16x4*)(&Kt[0][0] + (size_t)(t16 * 16 + lrow) * DH + 4 * lg);
        float4 mv = *(const float4*)(&mbs[t16 * 16 + 4 * lg]);
        f32x4 mc = {mv.x, mv.y, mv.z, mv.w};
        f16x4 vb = *(const f16x4*)(&Vt[lrow][t16 * 16 + 4 * lg]);

#pragma unroll
        for (int qt = 0; qt < QT; ++qt) {
            f32x4 s = __builtin_amdgcn_mfma_f32_16x16x16f16(kf, qf[qt], mc, 0, 0, 0);
            hf2 lo = __builtin_amdgcn_cvt_pkrtz(__builtin_amdgcn_exp2f(s[0]),
                                                __builtin_amdgcn_exp2f(s[1]));
            hf2 hi = __builtin_amdgcn_cvt_pkrtz(__builtin_amdgcn_exp2f(s[2]),
                                                __builtin_amdgcn_exp2f(s[3]));
            f16x4 pa;
            ((hf2*)&pa)[0] = lo;
            ((hf2*)&pa)[1] = hi;
            oacc[qt] = __builtin_amdgcn_mfma_f32_16x16x16f16(pa, vb, oacc[qt], 0, 0, 0);
        }
    }

    int d = lrow;
    size_t zoff = (size_t)blockIdx.z * B * N;
#pragma unroll
    for (int qt = 0; qt < QT; ++qt) {
#pragma unroll
        for (int r = 0; r < 4; ++r) {
            int q = qbase + qt * 16 + lg * 4 + r;
            float val = oacc[qt][r];
            if (d < DH)
                pacc[(zoff + bN + q) * LD + h * DH + d] = val;
            else if (d == DH)
                pl[(zoff + bN + q) * H + h] = val;
        }
    }
}

// ---------------------------------------------------------------------------
// fold1: d1 partials -> combine -> @Wf1 -> f16 head-major q2h/k2h/v2h
// ([BH][N][4], Q pre-scaled by qmul2). 16 rows/block.
// ---------------------------------------------------------------------------
__global__ __launch_bounds__(256) void fold1_kernel(
    const float* __restrict__ pacc, const float* __restrict__ pl,
    const float* __restrict__ Wf1, const float* __restrict__ bf1,
    f16* __restrict__ q2h, f16* __restrict__ k2h, f16* __restrict__ v2h,
    int BN, int N, int H, float qmul2) {
    int row0 = blockIdx.x * 16;
    int tid = threadIdx.x;
    __shared__ float comb[16][49];
    __shared__ float invl[16][4];
    if (tid < 64) {
        int r = tid >> 2, h = tid & 3;
        float ls = 0.f;
#pragma unroll
        for (int z = 0; z < 4; ++z) ls += pl[((size_t)z * BN + row0 + r) * 4 + h];
        invl[r][h] = 1.f / ls;
    }
    __syncthreads();
#pragma unroll
    for (int k = 0; k < 3; ++k) {      // 768 = 16 rows x 48 d
        int idx = tid + k * 256;
        int r = idx / 48, d = idx % 48;
        float a = 0.f;
#pragma unroll
        for (int z = 0; z < 4; ++z) a += pacc[((size_t)z * BN + row0 + r) * 48 + d];
        comb[r][d] = a * invl[r][d / 12];
    }
    __syncthreads();
#pragma unroll
    for (int k = 0; k < 3; ++k) {      // 768 = 3 mats x 16 rows x 16 c
        int idx = tid + k * 256;
        int mat = idx / 256, r = (idx % 256) / 16, c = idx % 16;
        float s = bf1[mat * 16 + c];
        const float* wcol = Wf1 + mat * 768 + c;
#pragma unroll
        for (int d = 0; d < 48; ++d)
            s = fmaf(comb[r][d], wcol[d * 16], s);
        int row = row0 + r;
        int b = row / N, n = row % N;
        int h = c >> 2, dd = c & 3;
        size_t off = ((size_t)(b * H + h) * N + n) * 4 + dd;
        if (mat == 0)      q2h[off] = (f16)(s * qmul2);
        else if (mat == 1) k2h[off] = (f16)s;
        else               v2h[off] = (f16)s;
    }
}

// ---------------------------------------------------------------------------
// fold2: d2 partials -> combine -> @Wfp/@Wfv -> f16 head-major pol/val QKV.
// 8 rows/block.
// ---------------------------------------------------------------------------
__global__ __launch_bounds__(256) void fold2_kernel(
    const float* __restrict__ pacc, const float* __restrict__ pl,
    const float* __restrict__ Wfp, const float* __restrict__ bfp,
    const float* __restrict__ Wfv, const float* __restrict__ bfv,
    f16* __restrict__ qph, f16* __restrict__ kph, f16* __restrict__ vph,
    f16* __restrict__ qvh, f16* __restrict__ kvh, f16* __restrict__ vvh,
    int BN, int N, int H, float qmul2) {
    int row0 = blockIdx.x * 8;
    int tid = threadIdx.x;
    __shared__ float comb[8][17];
    __shared__ float invl[8][4];
    if (tid < 32) {
        int r = tid >> 2, h = tid & 3;
        float ls = 0.f;
#pragma unroll
        for (int z = 0; z < 4; ++z) ls += pl[((size_t)z * BN + row0 + r) * 4 + h];
        invl[r][h] = 1.f / ls;
    }
    __syncthreads();
    if (tid < 128) {                   // 8 rows x 16 d
        int r = tid / 16, d = tid % 16;
        float a = 0.f;
#pragma unroll
        for (int z = 0; z < 4; ++z) a += pacc[((size_t)z * BN + row0 + r) * 16 + d];
        comb[r][d] = a * invl[r][d >> 2];
    }
    __syncthreads();
#pragma unroll
    for (int k = 0; k < 3; ++k) {      // 768 = 2 sets x 3 mats x 8 rows x 16 c
        int idx = tid + k * 256;
        int set = idx / 384;
        int rem = idx % 384;
        int mat = rem / 128, r = (rem % 128) / 16, c = rem % 16;
        const float* W  = set ? Wfv : Wfp;
        const float* bb = set ? bfv : bfp;
        float s = bb[mat * 16 + c];
        const float* wcol = W + mat * 256 + c;
#pragma unroll
        for (int d = 0; d < 16; ++d)
            s = fmaf(comb[r][d], wcol[d * 16], s);
        int row = row0 + r;
        int b = row / N, n = row % N;
        int h = c >> 2, dd = c & 3;
        size_t off = ((size_t)(b * H + h) * N + n) * 4 + dd;
        f16* dst;
        if (set == 0) dst = (mat == 0) ? qph : (mat == 1) ? kph : vph;
        else          dst = (mat == 0) ? qvh : (mat == 1) ? kvh : vvh;
        dst[off] = (f16)((mat == 0) ? s * qmul2 : s);
    }
}

// ---------------------------------------------------------------------------
// final2: blocks 0..B-1 compute action head (from pol partials) + masked
// softmax; blocks B..2B-1 compute value head (from val partials) + critic.
// ---------------------------------------------------------------------------
__global__ __launch_bounds__(256) void final2_kernel(
    const float* __restrict__ paccp, const float* __restrict__ plp,
    const float* __restrict__ paccv, const float* __restrict__ plv,
    const float* __restrict__ pol_wo, const float* __restrict__ pol_bo,
    const float* __restrict__ val_wo, const float* __restrict__ val_bo,
    const int* __restrict__ mask, const float* __restrict__ v2w,
    const float* __restrict__ v2b,
    float* __restrict__ out_action, float* __restrict__ out_critic,
    int N, int B, int BN) {
    int tid = threadIdx.x;
    if ((int)blockIdx.x < B) {
        int b = blockIdx.x;
        int lane = tid & 63, wid = tid >> 6;
        __shared__ float wred[4];
        __shared__ float sbcast;

        float local[4];
        float mx = -INFINITY;
#pragma unroll
        for (int i = 0; i < 4; ++i) {
            int row = b * N + tid + i * 256;
            float sa = pol_bo[0];
            float ls0 = 0.f, ls1 = 0.f, ls2 = 0.f, ls3 = 0.f;
#pragma unroll
            for (int z = 0; z < 4; ++z) {
                const float* plr = plp + ((size_t)z * BN + row) * 4;
                ls0 += plr[0]; ls1 += plr[1]; ls2 += plr[2]; ls3 += plr[3];
            }
            float inv[4] = {1.f / ls0, 1.f / ls1, 1.f / ls2, 1.f / ls3};
#pragma unroll
            for (int d = 0; d < 16; ++d) {
                float a = 0.f;
#pragma unroll
                for (int z = 0; z < 4; ++z)
                    a += paccp[((size_t)z * BN + row) * 16 + d];
                sa = fmaf(a * inv[d >> 2], pol_wo[d], sa);
            }
            float aa = (mask[row] == 0) ? NEGV : sa;
            local[i] = aa;
            mx = fmaxf(mx, aa);
        }
#pragma unroll
        for (int o = 32; o > 0; o >>= 1) mx = fmaxf(mx, __shfl_down(mx, o));
        if (lane == 0) wred[wid] = mx;
        __syncthreads();
        if (tid == 0) sbcast = fmaxf(fmaxf(wred[0], wred[1]), fmaxf(wred[2], wred[3]));
        __syncthreads();
        mx = sbcast;

        float s = 0.f;
#pragma unroll
        for (int i = 0; i < 4; ++i) {
            float p = __expf(local[i] - mx);
            local[i] = p;
            s += p;
        }
#pragma unroll
        for (int o = 32; o > 0; o >>= 1) s += __shfl_down(s, o);
        if (lane == 0) wred[wid] = s;
        __syncthreads();
        if (tid == 0) sbcast = wred[0] + wred[1] + wred[2] + wred[3];
        __syncthreads();
        float inv = 1.f / sbcast;
#pragma unroll
        for (int i = 0; i < 4; ++i) out_action[b * N + tid + i * 256] = local[i] * inv;
    } else {
        int b = blockIdx.x - B;
        __shared__ float cr[1024];
        __shared__ float red[16][17];
#pragma unroll
        for (int i = 0; i < 4; ++i) {
            int idx = tid + i * 256;
            int row = b * N + idx;
            float sc = val_bo[0];
            float ls0 = 0.f, ls1 = 0.f, ls2 = 0.f, ls3 = 0.f;
#pragma unroll
            for (int z = 0; z < 4; ++z) {
                const float* plr = plv + ((size_t)z * BN + row) * 4;
                ls0 += plr[0]; ls1 += plr[1]; ls2 += plr[2]; ls3 += plr[3];
            }
            float inv[4] = {1.f / ls0, 1.f / ls1, 1.f / ls2, 1.f / ls3};
#pragma unroll
            for (int d = 0; d < 16; ++d) {
                float a = 0.f;
#pragma unroll
                for (int z = 0; z < 4; ++z)
                    a += paccv[((size_t)z * BN + row) * 16 + d];
                sc = fmaf(a * inv[d >> 2], val_wo[d], sc);
            }
            cr[idx] = sc;
        }
        __syncthreads();
        int c = tid & 15, seg = tid >> 4;
        float s = 0.f;
        int n0 = seg * 64;
        for (int n = n0; n < n0 + 64; ++n)
            s = fmaf(cr[n], v2w[n * 16 + c], s);
        red[seg][c] = s;
        __syncthreads();
        if (tid < 16) {
            float acc = v2b[tid];
#pragma unroll
            for (int g = 0; g < 16; ++g) acc += red[g][tid];
            out_critic[b * 16 + tid] = acc;
        }
    }
}

// ---------------------------------------------------------------------------
extern "C" void kernel_launch(void* const* d_in, const int* in_sizes, int n_in,
                              void* d_out, int out_size, void* d_ws, size_t ws_size,
                              hipStream_t stream) {
    const int B = 16, M = 32, F = 16, H = 4;
    const int N = M * M;          // 1024
    const int BN = B * N;         // 16384
    const int BHN = B * H * N;    // 65536
    const int KSPLIT = 4;         // MUST equal N/256

    const float* r1       = (const float*)d_in[0];
    const float* r2       = (const float*)d_in[1];
    const float* edge     = (const float*)d_in[2];
    const int*   mask     = (const int*)d_in[3];
    const float* d1_wqkv  = (const float*)d_in[4];
    const float* d1_bqkv  = (const float*)d_in[5];
    const float* d1_wo    = (const float*)d_in[6];
    const float* d1_bo    = (const float*)d_in[7];
    const float* d2_wqkv  = (const float*)d_in[8];
    const float* d2_bqkv  = (const float*)d_in[9];
    const float* d2_wo    = (const float*)d_in[10];
    const float* d2_bo    = (const float*)d_in[11];
    const float* pol_wqkv = (const float*)d_in[12];
    const float* pol_bqkv = (const float*)d_in[13];
    const float* pol_wo   = (const float*)d_in[14];
    const float* pol_bo   = (const float*)d_in[15];
    const float* val_wqkv = (const float*)d_in[16];
    const float* val_bqkv = (const float*)d_in[17];
    const float* val_wo   = (const float*)d_in[18];
    const float* val_bo   = (const float*)d_in[19];
    const float* v2_w     = (const float*)d_in[20];
    const float* v2_b     = (const float*)d_in[21];

    float* ws = (float*)d_ws;
    float* pacc = ws;                               // 4*BN*48
    float* plp  = pacc + 4 * BN * 48;               // 4*BN*4
    float* plv  = plp + 4 * BN * 4;                 // 4*BN*4
    float* Wf1  = plv + 4 * BN * 4;                 // 2304
    float* bf1  = Wf1 + 2304;                       // 48
    float* Wfp  = bf1 + 48;                         // 768
    float* bfp  = Wfp + 768;                        // 48
    float* Wfv  = bfp + 48;                         // 768
    float* bfv  = Wfv + 768;                        // 48
    f16* fh  = (f16*)(bfv + 48);
    f16* q1h = fh;                                  // BHN*12
    f16* k1h = q1h + (size_t)BHN * 12;
    f16* v1h = k1h + (size_t)BHN * 12;
    f16* q2h = v1h + (size_t)BHN * 12;              // BHN*4 each from here
    f16* k2h = q2h + (size_t)BHN * 4;
    f16* v2h = k2h + (size_t)BHN * 4;
    f16* qph = v2h + (size_t)BHN * 4;
    f16* kph = qph + (size_t)BHN * 4;
    f16* vph = kph + (size_t)BHN * 4;
    f16* qvh = vph + (size_t)BHN * 4;
    f16* kvh = qvh + (size_t)BHN * 4;
    f16* vvh = kvh + (size_t)BHN * 4;
    // pol/val pacc split inside the big pacc buffer
    float* paccp = pacc;
    float* paccv = pacc + (size_t)KSPLIT * BN * 16;

    float* out_action = (float*)d_out;              // B*N
    float* out_critic = out_action + BN;            // B*16

    const float qmul1 = (1.0f / sqrtf(12.0f)) * LOG2E;
    const float qmul2 = 0.5f * LOG2E;

    // 1. d1 QKV (f16 head-major) + folded-weight prep
    {
        int mainBlocks = (3 * BN * 48 + 255) / 256;
        qkv1_prep_kernel<<<mainBlocks + 16, 256, 0, stream>>>(
            r1, r2, edge, d1_wqkv, d1_bqkv, d1_wo, d1_bo,
            d2_wqkv, d2_bqkv, d2_wo, d2_bo,
            pol_wqkv, pol_bqkv, val_wqkv, val_bqkv,
            q1h, k1h, v1h, Wf1, bf1, Wfp, bfp, Wfv, bfv,
            B, M, F, H, qmul1, mainBlocks);
    }
    // 2. d1 attention
    attn_h_kernel<12, 2><<<dim3(B * H, N / 128, KSPLIT), 256, 0, stream>>>(
        q1h, k1h, v1h, q1h, k1h, v1h, mask,
        pacc, plp, pacc, plp, B, H, N);
    // 3. fold1 -> d2 QKV (f16 head-major)
    fold1_kernel<<<BN / 16, 256, 0, stream>>>(
        pacc, plp, Wf1, bf1, q2h, k2h, v2h, BN, N, H, qmul2);
    // 4. d2 attention
    attn_h_kernel<4, 2><<<dim3(B * H, N / 128, KSPLIT), 256, 0, stream>>>(
        q2h, k2h, v2h, q2h, k2h, v2h, mask,
        pacc, plp, pacc, plp, B, H, N);
    // 5. fold2 -> pol/val QKV (f16 head-major)
    fold2_kernel<<<BN / 8, 256, 0, stream>>>(
        pacc, plp, Wfp, bfp, Wfv, bfv,
        qph, kph, vph, qvh, kvh, vvh, BN, N, H, qmul2);
    // 6. pol + val attention (two sets in one launch)
    attn_h_kernel<4, 2><<<dim3(2 * B * H, N / 128, KSPLIT), 256, 0, stream>>>(
        qph, kph, vph, qvh, kvh, vvh, mask,
        paccp, plp, paccv, plv, B, H, N);
    // 7. heads + masked softmax + critic
    final2_kernel<<<2 * B, 256, 0, stream>>>(
        paccp, plp, paccv, plv, pol_wo, pol_bo, val_wo, val_bo,
        mask, v2_w, v2_b, out_action, out_critic, N, B, BN);
}